// Round 1
// baseline (311.261 us; speedup 1.0000x reference)
//
#include <hip/hip_runtime.h>
#include <math.h>

#define FBINS 2112   // 64 * 33 frequency bins per (image, channel)

typedef float2 cplx;

__device__ __forceinline__ cplx cmul(cplx a, cplx b) {
    return make_float2(a.x*b.x - a.y*b.y, a.x*b.y + a.y*b.x);
}

// 64-point complex DFT, cooperative among 8 threads (j = 0..7), radix 8x8.
// Data at lds[base + k*stride], k = 0..63, natural order in and out.
// tw[m] = exp(sign * 2*pi*i*m/64)  (sign = -1 forward, +1 inverse).
// Contains __syncthreads -> ALL threads of the block must call it; threads
// that have no column to process pass active=false (they still hit barriers).
__device__ void fft64_8(cplx* lds, int base, int stride, int j, const cplx* tw, bool active)
{
    cplx v[8];
    if (active) {
        #pragma unroll
        for (int n1 = 0; n1 < 8; ++n1) v[n1] = lds[base + (8*n1 + j)*stride];
    }
    __syncthreads();   // protect in-place overwrite of other threads' inputs
    if (active) {
        // stage 1: thread j plays role n2=j. A[n2][k1] stored at index n2*8+k1.
        #pragma unroll
        for (int k1 = 0; k1 < 8; ++k1) {
            cplx acc = make_float2(0.f, 0.f);
            #pragma unroll
            for (int n1 = 0; n1 < 8; ++n1) {
                cplx w = tw[(8*n1*k1) & 63];           // W8^{n1*k1}
                acc.x += v[n1].x*w.x - v[n1].y*w.y;
                acc.y += v[n1].x*w.y + v[n1].y*w.x;
            }
            acc = cmul(acc, tw[(j*k1) & 63]);          // twiddle W64^{n2*k1}
            lds[base + (j*8 + k1)*stride] = acc;
        }
    }
    __syncthreads();
    if (active) {
        // stage 2: thread j plays role k1=j. out[k1+8*k2]; slot k2*8+j is
        // read only by this same thread (already in regs) -> no barrier.
        cplx a[8];
        #pragma unroll
        for (int n2 = 0; n2 < 8; ++n2) a[n2] = lds[base + (n2*8 + j)*stride];
        #pragma unroll
        for (int k2 = 0; k2 < 8; ++k2) {
            cplx acc = make_float2(0.f, 0.f);
            #pragma unroll
            for (int n2 = 0; n2 < 8; ++n2) {
                cplx w = tw[(8*n2*k2) & 63];           // W8^{n2*k2}
                acc.x += a[n2].x*w.x - a[n2].y*w.y;
                acc.y += a[n2].x*w.y + a[n2].y*w.x;
            }
            lds[base + (j + 8*k2)*stride] = acc;
        }
    }
}

// Forward rfft2 of one 64x64 real image per block. Output: 64x33 complex,
// flat layout out[img*2112 + h*33 + w'], scaled by `scale`.
__global__ __launch_bounds__(256) void fwd_fft_kernel(
    const float* __restrict__ in, cplx* __restrict__ out, float scale)
{
    __shared__ cplx D[64*64];
    __shared__ cplx tw[64];
    const int tid = threadIdx.x;
    const int g = tid >> 3, j = tid & 7;

    if (tid < 64) {
        float s, c;
        sincosf(-6.283185307179586f * (float)tid / 64.0f, &s, &c);
        tw[tid] = make_float2(c, s);                   // forward twiddles
    }
    const float* img = in + (size_t)blockIdx.x * 4096;
    for (int i = tid; i < 4096; i += 256) D[i] = make_float2(img[i], 0.f);
    __syncthreads();

    // row FFTs (along W), 64 rows in 2 passes of 32 groups
    fft64_8(D, g * 64,        1, j, tw, true);
    __syncthreads();
    fft64_8(D, (g + 32) * 64, 1, j, tw, true);
    __syncthreads();
    // column FFTs (along H) for w' = 0..32
    fft64_8(D, g,  64, j, tw, true);                   // w' = 0..31
    __syncthreads();
    fft64_8(D, 32, 64, j, tw, g == 0);                 // w' = 32 (group 0 only)
    __syncthreads();

    cplx* o = out + (size_t)blockIdx.x * FBINS;
    for (int i = tid; i < FBINS; i += 256) {
        int h = i / 33, wp = i % 33;
        cplx v = D[h*64 + wp];
        o[i] = make_float2(v.x * scale, v.y * scale);
    }
}

// Norms: blocks 0..31 -> ||x_b||, blocks 32..543 -> ||y_n||
__global__ __launch_bounds__(256) void norm_kernel(
    const float* __restrict__ x, const float* __restrict__ y,
    float* __restrict__ xn, float* __restrict__ yn)
{
    __shared__ float red[4];
    const int blk = blockIdx.x;
    const float* p = (blk < 32) ? x + (size_t)blk * 12288
                                : y + (size_t)(blk - 32) * 12288;
    const float4* p4 = (const float4*)p;
    float s = 0.f;
    for (int i = threadIdx.x; i < 3072; i += 256) {
        float4 v = p4[i];
        s += v.x*v.x + v.y*v.y + v.z*v.z + v.w*v.w;
    }
    #pragma unroll
    for (int off = 32; off; off >>= 1) s += __shfl_xor(s, off);
    if ((threadIdx.x & 63) == 0) red[threadIdx.x >> 6] = s;
    __syncthreads();
    if (threadIdx.x == 0) {
        float t = red[0] + red[1] + red[2] + red[3];
        if (blk < 32) xn[blk] = sqrtf(t); else yn[blk - 32] = sqrtf(t);
    }
}

// Main kernel: one block per (b,n) pair. blk = b*512 + n.
__global__ __launch_bounds__(256) void corr_kernel(
    const cplx* __restrict__ Xf, const cplx* __restrict__ Yf,
    const float* __restrict__ xn, const float* __restrict__ yn,
    float* __restrict__ out)
{
    __shared__ cplx S[FBINS];      // G[h][w'] at h*33+w'
    __shared__ cplx Zr[32*64];     // row-FFT stage-1 workspace
    __shared__ cplx tw[64];        // inverse twiddles
    __shared__ float red[4];

    const int tid = threadIdx.x;
    const int g = tid >> 3, j = tid & 7;
    const int blk = blockIdx.x;
    const int b = blk >> 9;        // /512
    const int n = blk & 511;

    if (tid < 64) {
        float s, c;
        sincosf(6.283185307179586f * (float)tid / 64.0f, &s, &c);
        tw[tid] = make_float2(c, s);                   // inverse twiddles
    }

    // ---- step A: G[h][w'] = sum_c conj(X[b,c]) * Y[n,c]  (1/4096 folded in X)
    const cplx* Xb = Xf + (size_t)b * 3 * FBINS;
    const cplx* Yn = Yf + (size_t)n * 3 * FBINS;
    for (int i = tid; i < FBINS; i += 256) {
        float2 acc = make_float2(0.f, 0.f);
        #pragma unroll
        for (int ch = 0; ch < 3; ++ch) {
            float2 a  = Xb[ch*FBINS + i];
            float2 bb = Yn[ch*FBINS + i];
            acc.x += a.x*bb.x + a.y*bb.y;              // conj(a)*b
            acc.y += a.x*bb.y - a.y*bb.x;
        }
        S[i] = acc;
    }
    __syncthreads();

    // ---- step B: inverse FFT along H on each column.
    // Columns 0 and 32 have real IFFTs (Hermitian in h) -> pack into one
    // complex FFT in column 0's slots: z[h] = col0[h] + i*col32[h].
    if (g == 0) {
        #pragma unroll
        for (int n1 = 0; n1 < 8; ++n1) {
            int h = 8*n1 + j;                          // exactly the slots this
            float2 a  = S[h*33 + 0];                   // thread loads in stage 1
            float2 bb = S[h*33 + 32];
            S[h*33 + 0] = make_float2(a.x - bb.y, a.y + bb.x);
        }
    }
    fft64_8(S, g, 33, j, tw, true);   // column g (g==0 is the packed pair)
    __syncthreads();
    // Now: S[h][0] = (c0[h], c32[h]) (both real series), S[h][w'] w'=1..31 complex.

    // ---- step C: inverse FFT along W, rows packed pairwise (r1=g, r2=g+32).
    // Row spectrum R[w]: R[0]=S[r][0].x, R[32]=S[r][0].y, R[w]=S[r][w] (1..31),
    // R[w]=conj(R[64-w]) (33..63). z[w] = R_{r1}[w] + i*R_{r2}[w].
    {
        const int r1 = g, r2 = g + 32;
        cplx v[8];
        #pragma unroll
        for (int n1 = 0; n1 < 8; ++n1) {
            int w = 8*n1 + j;
            float2 xp;
            if (w == 0) {
                xp = make_float2(S[r1*33].x, S[r2*33].x);
            } else if (w == 32) {
                xp = make_float2(S[r1*33].y, S[r2*33].y);
            } else if (w < 32) {
                float2 a = S[r1*33 + w], bb = S[r2*33 + w];
                xp = make_float2(a.x - bb.y, a.y + bb.x);
            } else {
                float2 a = S[r1*33 + (64-w)], bb = S[r2*33 + (64-w)];
                xp = make_float2(a.x + bb.y, -a.y + bb.x);   // conj-extended
            }
            v[n1] = xp;
        }
        // stage 1 into Zr
        #pragma unroll
        for (int k1 = 0; k1 < 8; ++k1) {
            cplx acc = make_float2(0.f, 0.f);
            #pragma unroll
            for (int n1 = 0; n1 < 8; ++n1) {
                cplx w8 = tw[(8*n1*k1) & 63];
                acc.x += v[n1].x*w8.x - v[n1].y*w8.y;
                acc.y += v[n1].x*w8.y + v[n1].y*w8.x;
            }
            acc = cmul(acc, tw[(j*k1) & 63]);
            Zr[g*64 + j*8 + k1] = acc;
        }
        __syncthreads();
        // stage 2: outputs are g-values of rows r1 (re) and r2 (im) -> max only
        float m = -3.4e38f;
        cplx a[8];
        #pragma unroll
        for (int n2 = 0; n2 < 8; ++n2) a[n2] = Zr[g*64 + n2*8 + j];
        #pragma unroll
        for (int k2 = 0; k2 < 8; ++k2) {
            cplx acc = make_float2(0.f, 0.f);
            #pragma unroll
            for (int n2 = 0; n2 < 8; ++n2) {
                cplx w8 = tw[(8*n2*k2) & 63];
                acc.x += a[n2].x*w8.x - a[n2].y*w8.y;
                acc.y += a[n2].x*w8.y + a[n2].y*w8.x;
            }
            m = fmaxf(m, fmaxf(acc.x, acc.y));
        }
        // block-wide max reduction
        #pragma unroll
        for (int off = 32; off; off >>= 1) m = fmaxf(m, __shfl_xor(m, off));
        if ((tid & 63) == 0) red[tid >> 6] = m;
        __syncthreads();
        if (tid == 0) {
            float mm = fmaxf(fmaxf(red[0], red[1]), fmaxf(red[2], red[3]));
            out[blk] = mm / (xn[b] * yn[n]);
        }
    }
}

extern "C" void kernel_launch(void* const* d_in, const int* in_sizes, int n_in,
                              void* d_out, int out_size, void* d_ws, size_t ws_size,
                              hipStream_t stream) {
    const float* x = (const float*)d_in[0];   // (32,3,64,64)
    const float* y = (const float*)d_in[1];   // (512,3,64,64)
    float* out = (float*)d_out;               // (32,512)

    // workspace layout: Xf[96*2112] cplx | Yf[1536*2112] cplx | xn[32] | yn[512]
    cplx* Xf = (cplx*)d_ws;
    cplx* Yf = Xf + 96 * FBINS;
    float* xn = (float*)(Yf + 1536 * FBINS);
    float* yn = xn + 32;

    // forward FFTs (1/4096 IFFT normalization folded into X)
    fwd_fft_kernel<<<96,   256, 0, stream>>>(x, Xf, 1.0f / 4096.0f);
    fwd_fft_kernel<<<1536, 256, 0, stream>>>(y, Yf, 1.0f);
    norm_kernel<<<544, 256, 0, stream>>>(x, y, xn, yn);
    corr_kernel<<<16384, 256, 0, stream>>>(Xf, Yf, xn, yn, out);
}

// Round 2
// 134.844 us; speedup vs baseline: 2.3083x; 2.3083x over previous
//
#include <hip/hip_runtime.h>
#include <math.h>

#define FBINS 2112            // 33 * 64 bins, layout: bin = w'*64 + h
#define CSTRIDE 67            // LDS column stride in floats (67 % 32 == 3)

typedef float2 cplx;

__device__ __forceinline__ cplx cadd(cplx a, cplx b){ return make_float2(a.x+b.x, a.y+b.y); }
__device__ __forceinline__ cplx csub(cplx a, cplx b){ return make_float2(a.x-b.x, a.y-b.y); }
__device__ __forceinline__ cplx cmul(cplx a, cplx b){ return make_float2(a.x*b.x - a.y*b.y, a.x*b.y + a.y*b.x); }
template<int S> __device__ __forceinline__ cplx imul(cplx a){   // (i*S) * a
    return (S > 0) ? make_float2(-a.y, a.x) : make_float2(a.y, -a.x);
}

// Hardcoded 8-point DFT: X[k] = sum_n v[n] * w8^(n*k), w8 = exp(i*S*pi/4).
template<int S>
__device__ __forceinline__ void dft8(cplx v[8]) {
    const float C = 0.70710678118654752440f;
    cplx t0=cadd(v[0],v[4]), t4=csub(v[0],v[4]);
    cplx t1=cadd(v[1],v[5]), t5=csub(v[1],v[5]);
    cplx t2=cadd(v[2],v[6]), t6=csub(v[2],v[6]);
    cplx t3=cadd(v[3],v[7]), t7=csub(v[3],v[7]);
    cplx u0=cadd(t0,t2), u2=csub(t0,t2);
    cplx u1=cadd(t1,t3), u3=csub(t1,t3);
    v[0]=cadd(u0,u1); v[4]=csub(u0,u1);
    cplx m3=imul<S>(u3);
    v[2]=cadd(u2,m3); v[6]=csub(u2,m3);
    // odd part: z = {t4, w8*t5, (iS)*t6, w8^3*t7}
    cplx z0=t4;
    cplx z1 = (S>0) ? make_float2(C*(t5.x-t5.y), C*(t5.y+t5.x))
                    : make_float2(C*(t5.x+t5.y), C*(t5.y-t5.x));
    cplx z2 = imul<S>(t6);
    cplx z3 = (S>0) ? make_float2(C*(-t7.x-t7.y), C*( t7.x-t7.y))
                    : make_float2(C*(-t7.x+t7.y), C*(-t7.x-t7.y));
    cplx w0=cadd(z0,z2), w2=csub(z0,z2);
    cplx w1=cadd(z1,z3), w3=csub(z1,z3);
    v[1]=cadd(w0,w1); v[5]=csub(w0,w1);
    cplx mb=imul<S>(w3);
    v[3]=cadd(w2,mb); v[7]=csub(w2,mb);
}

// Cooperative 64-point DFT among 8 same-wave lanes (j = 0..7), inputs already
// in regs as v[n1] = z[8*n1 + j]. Uses LDS column [base..base+63] as scratch
// (stage-1 exchange). On return v[k2] = X[j + 8*k2]. Same-wave lockstep makes
// the in-column read/write ordering safe without barriers.
template<int S>
__device__ __forceinline__ void fft64_from_regs(
    cplx v[8], float* __restrict__ re, float* __restrict__ im,
    int base, int j, const cplx wj[7])
{
    dft8<S>(v);                       // A[j][k1], k1 = reg index
    #pragma unroll
    for (int k=1;k<8;++k) v[k] = cmul(v[k], wj[k-1]);   // * w64^(j*k1)
    #pragma unroll
    for (int k=0;k<8;++k){ int s=base+8*j+k; re[s]=v[k].x; im[s]=v[k].y; }
    #pragma unroll
    for (int n=0;n<8;++n){ int s=base+8*n+j; v[n]=make_float2(re[s],im[s]); }
    dft8<S>(v);                       // X[j + 8*k2]
}

template<int S>
__device__ __forceinline__ void make_twiddles(int j, cplx wj[7]) {
    float sn, cs;
    sincosf((float)S * 6.283185307179586f * (float)j / 64.0f, &sn, &cs);
    cplx w1 = make_float2(cs, sn);
    wj[0] = w1;
    #pragma unroll
    for (int k=1;k<7;++k) wj[k] = cmul(wj[k-1], w1);
}

// Forward rfft2 of one 64x64 real image per block.
// Output layout: out[img*2112 + w'*64 + h], scaled by `scale`.
__global__ __launch_bounds__(256) void fwd_fft_kernel(
    const float* __restrict__ in, cplx* __restrict__ out, float scale)
{
    __shared__ float SRe[33*CSTRIDE], SIm[33*CSTRIDE];
    const int tid = threadIdx.x, G = tid>>3, j = tid&7;
    cplx wj[7]; make_twiddles<-1>(j, wj);

    const float* img = in + (size_t)blockIdx.x * 4096;

    // row pass: pack rows (G, G+32): z[w] = row_G[w] + i*row_{G+32}[w]
    {
        cplx v[8];
        #pragma unroll
        for (int nn=0;nn<8;++nn){ int w=8*nn+j;
            v[nn] = make_float2(img[64*G + w], img[64*(G+32) + w]); }
        int base = CSTRIDE*G;
        fft64_from_regs<-1>(v, SRe, SIm, base, j, wj);
        #pragma unroll
        for (int k=0;k<8;++k){ int s=base+j+8*k; SRe[s]=v[k].x; SIm[s]=v[k].y; }
    }
    __syncthreads();

    // column pass: group 0 handles packed columns (0,32); group G -> column G.
    {
        cplx v[8];
        if (G == 0) {
            #pragma unroll
            for (int nn=0;nn<8;++nn){
                int r=8*nn+j, p=r&31, hi=r>>5;
                float a0 =SRe[CSTRIDE*p + 0],  b0 =SIm[CSTRIDE*p + 0];
                float a32=SRe[CSTRIDE*p + 32], b32=SIm[CSTRIDE*p + 32];
                v[nn] = hi ? make_float2(b0, b32) : make_float2(a0, a32);
            }
        } else {
            const int c = G;
            #pragma unroll
            for (int nn=0;nn<8;++nn){
                int r=8*nn+j, p=r&31, hi=r>>5;
                cplx A  = make_float2(SRe[CSTRIDE*p + c],      SIm[CSTRIDE*p + c]);
                cplx Bm = make_float2(SRe[CSTRIDE*p + 64 - c], SIm[CSTRIDE*p + 64 - c]);
                if (!hi) v[nn] = make_float2(0.5f*(A.x + Bm.x), 0.5f*(A.y - Bm.y));
                else { float dx = A.x - Bm.x, dy = A.y + Bm.y;
                       v[nn] = make_float2(0.5f*dy, -0.5f*dx); }
            }
        }
        __syncthreads();              // row-pass data fully consumed into regs
        int base = CSTRIDE*G;
        fft64_from_regs<-1>(v, SRe, SIm, base, j, wj);
        #pragma unroll
        for (int k=0;k<8;++k){ int s=base+j+8*k; SRe[s]=v[k].x; SIm[s]=v[k].y; }
    }
    __syncthreads();

    // unpack packed column 0 -> true columns 0 and 32; store all.
    cplx* o = out + (size_t)blockIdx.x * FBINS;
    for (int i = tid; i < FBINS; i += 256) {
        int wp = i>>6, h = i&63;
        cplx r;
        if (wp == 0) {
            int h2 = (64-h)&63;
            cplx a = make_float2(SRe[h],  SIm[h]);
            cplx bb= make_float2(SRe[h2], SIm[h2]);
            r = make_float2(0.5f*(a.x+bb.x), 0.5f*(a.y-bb.y));
        } else if (wp == 32) {
            int h2 = (64-h)&63;
            cplx a = make_float2(SRe[h],  SIm[h]);
            cplx bb= make_float2(SRe[h2], SIm[h2]);
            float dx = a.x-bb.x, dy = a.y+bb.y;
            r = make_float2(0.5f*dy, -0.5f*dx);
        } else {
            r = make_float2(SRe[CSTRIDE*wp + h], SIm[CSTRIDE*wp + h]);
        }
        o[i] = make_float2(r.x*scale, r.y*scale);
    }
}

__global__ __launch_bounds__(256) void norm_kernel(
    const float* __restrict__ x, const float* __restrict__ y,
    float* __restrict__ xn, float* __restrict__ yn)
{
    __shared__ float red[4];
    const int blk = blockIdx.x;
    const float* p = (blk < 32) ? x + (size_t)blk * 12288
                                : y + (size_t)(blk - 32) * 12288;
    const float4* p4 = (const float4*)p;
    float s = 0.f;
    for (int i = threadIdx.x; i < 3072; i += 256) {
        float4 v = p4[i];
        s += v.x*v.x + v.y*v.y + v.z*v.z + v.w*v.w;
    }
    #pragma unroll
    for (int off = 32; off; off >>= 1) s += __shfl_xor(s, off);
    if ((threadIdx.x & 63) == 0) red[threadIdx.x >> 6] = s;
    __syncthreads();
    if (threadIdx.x == 0) {
        float t = red[0] + red[1] + red[2] + red[3];
        if (blk < 32) xn[blk] = sqrtf(t); else yn[blk - 32] = sqrtf(t);
    }
}

// One block per (b,n) pair, XCD-tiled: XCD x owns n in [64x, 64x+64).
__global__ __launch_bounds__(256) void corr_kernel(
    const cplx* __restrict__ Xf, const cplx* __restrict__ Yf,
    const float* __restrict__ xn, const float* __restrict__ yn,
    float* __restrict__ out)
{
    __shared__ float SRe[33*CSTRIDE], SIm[33*CSTRIDE];
    __shared__ float red[4];
    const int tid = threadIdx.x, G = tid>>3, j = tid&7;

    const int blk = blockIdx.x;
    const int xcd = blk & 7, idx = blk >> 3;
    const int n = xcd*64 + (idx & 63);
    const int b = idx >> 6;

    cplx wj[7]; make_twiddles<1>(j, wj);

    // step A: G[h][w'] = sum_c conj(X)*Y, write to column-major SoA LDS
    const cplx* Xb = Xf + (size_t)b * 3 * FBINS;
    const cplx* Yn = Yf + (size_t)n * 3 * FBINS;
    #pragma unroll
    for (int t = 0; t < 9; ++t) {
        int i = tid + t*256;
        if (i < FBINS) {
            float ax = 0.f, ay = 0.f;
            #pragma unroll
            for (int ch = 0; ch < 3; ++ch) {
                cplx a = Xb[ch*FBINS + i];
                cplx c = Yn[ch*FBINS + i];
                ax += a.x*c.x + a.y*c.y;      // conj(a)*c
                ay += a.x*c.y - a.y*c.x;
            }
            int s = CSTRIDE*(i>>6) + (i&63);
            SRe[s] = ax; SIm[s] = ay;
        }
    }
    __syncthreads();

    // step B: inverse FFT along h per column; group 0 packs cols 0 & 32.
    {
        cplx v[8];
        int base = CSTRIDE*G;
        if (G == 0) {
            #pragma unroll
            for (int nn=0;nn<8;++nn){
                int h = 8*nn + j;
                cplx a = make_float2(SRe[h],               SIm[h]);
                cplx c = make_float2(SRe[CSTRIDE*32 + h],  SIm[CSTRIDE*32 + h]);
                v[nn] = make_float2(a.x - c.y, a.y + c.x);  // a + i*c
            }
        } else {
            #pragma unroll
            for (int nn=0;nn<8;++nn){ int s = base + 8*nn + j;
                v[nn] = make_float2(SRe[s], SIm[s]); }
        }
        fft64_from_regs<1>(v, SRe, SIm, base, j, wj);
        #pragma unroll
        for (int k=0;k<8;++k){ int s = base + j + 8*k; SRe[s]=v[k].x; SIm[s]=v[k].y; }
    }
    __syncthreads();
    // column 0 now holds (c0[h], c32[h]) real pair; cols 1..31 complex.

    // step C: inverse FFT along w, rows packed pairwise (r1=G, r2=G+32).
    float m = -3.4e38f;
    {
        const int r1 = G, r2 = G + 32;
        cplx v[8];
        // nn = 0: w = j
        if (j == 0) {
            v[0] = make_float2(SRe[r1], SRe[r2]);             // w=0: c0 pair
        } else {
            cplx a = make_float2(SRe[CSTRIDE*j + r1], SIm[CSTRIDE*j + r1]);
            cplx c = make_float2(SRe[CSTRIDE*j + r2], SIm[CSTRIDE*j + r2]);
            v[0] = make_float2(a.x - c.y, a.y + c.x);
        }
        #pragma unroll
        for (int nn=1; nn<4; ++nn) {                          // w = 8..31
            int w = 8*nn + j;
            cplx a = make_float2(SRe[CSTRIDE*w + r1], SIm[CSTRIDE*w + r1]);
            cplx c = make_float2(SRe[CSTRIDE*w + r2], SIm[CSTRIDE*w + r2]);
            v[nn] = make_float2(a.x - c.y, a.y + c.x);
        }
        // nn = 4: w = 32 + j
        if (j == 0) {
            v[4] = make_float2(SIm[r1], SIm[r2]);             // w=32: c32 pair
        } else {
            int w2 = 32 - j;
            cplx a = make_float2(SRe[CSTRIDE*w2 + r1], SIm[CSTRIDE*w2 + r1]);
            cplx c = make_float2(SRe[CSTRIDE*w2 + r2], SIm[CSTRIDE*w2 + r2]);
            v[4] = make_float2(a.x + c.y, -a.y + c.x);        // conj ext
        }
        #pragma unroll
        for (int nn=5; nn<8; ++nn) {                          // w = 40..63
            int w2 = 64 - (8*nn + j);
            cplx a = make_float2(SRe[CSTRIDE*w2 + r1], SIm[CSTRIDE*w2 + r1]);
            cplx c = make_float2(SRe[CSTRIDE*w2 + r2], SIm[CSTRIDE*w2 + r2]);
            v[nn] = make_float2(a.x + c.y, -a.y + c.x);
        }
        __syncthreads();              // all rows consumed; S becomes scratch
        fft64_from_regs<1>(v, SRe, SIm, CSTRIDE*G, j, wj);
        #pragma unroll
        for (int k=0;k<8;++k) m = fmaxf(m, fmaxf(v[k].x, v[k].y));
    }
    #pragma unroll
    for (int off = 32; off; off >>= 1) m = fmaxf(m, __shfl_xor(m, off));
    if ((tid & 63) == 0) red[tid >> 6] = m;
    __syncthreads();
    if (tid == 0) {
        float mm = fmaxf(fmaxf(red[0], red[1]), fmaxf(red[2], red[3]));
        out[b*512 + n] = mm / (xn[b] * yn[n]);
    }
}

extern "C" void kernel_launch(void* const* d_in, const int* in_sizes, int n_in,
                              void* d_out, int out_size, void* d_ws, size_t ws_size,
                              hipStream_t stream) {
    const float* x = (const float*)d_in[0];   // (32,3,64,64)
    const float* y = (const float*)d_in[1];   // (512,3,64,64)
    float* out = (float*)d_out;               // (32,512)

    cplx* Xf = (cplx*)d_ws;
    cplx* Yf = Xf + 96 * FBINS;
    float* xn = (float*)(Yf + 1536 * FBINS);
    float* yn = xn + 32;

    fwd_fft_kernel<<<96,   256, 0, stream>>>(x, Xf, 1.0f / 4096.0f);
    fwd_fft_kernel<<<1536, 256, 0, stream>>>(y, Yf, 1.0f);
    norm_kernel<<<544, 256, 0, stream>>>(x, y, xn, yn);
    corr_kernel<<<16384, 256, 0, stream>>>(Xf, Yf, xn, yn, out);
}

// Round 3
// 116.407 us; speedup vs baseline: 2.6739x; 1.1584x over previous
//
#include <hip/hip_runtime.h>
#include <math.h>

#define FBINS 2112            // 33 * 64 bins, layout: bin = w'*64 + h
#define CS 72                 // LDS column stride in floats; 72 % 32 == 8

typedef float2 cplx;

__device__ __forceinline__ cplx cadd(cplx a, cplx b){ return make_float2(a.x+b.x, a.y+b.y); }
__device__ __forceinline__ cplx csub(cplx a, cplx b){ return make_float2(a.x-b.x, a.y-b.y); }
__device__ __forceinline__ cplx cmul(cplx a, cplx b){ return make_float2(a.x*b.x - a.y*b.y, a.x*b.y + a.y*b.x); }
template<int S> __device__ __forceinline__ cplx imul(cplx a){   // (i*S) * a
    return (S > 0) ? make_float2(-a.y, a.x) : make_float2(a.y, -a.x);
}

// Hardcoded 8-point DFT: X[k] = sum_n v[n] * w8^(n*k), w8 = exp(i*S*pi/4).
template<int S>
__device__ __forceinline__ void dft8(cplx v[8]) {
    const float C = 0.70710678118654752440f;
    cplx t0=cadd(v[0],v[4]), t4=csub(v[0],v[4]);
    cplx t1=cadd(v[1],v[5]), t5=csub(v[1],v[5]);
    cplx t2=cadd(v[2],v[6]), t6=csub(v[2],v[6]);
    cplx t3=cadd(v[3],v[7]), t7=csub(v[3],v[7]);
    cplx u0=cadd(t0,t2), u2=csub(t0,t2);
    cplx u1=cadd(t1,t3), u3=csub(t1,t3);
    v[0]=cadd(u0,u1); v[4]=csub(u0,u1);
    cplx m3=imul<S>(u3);
    v[2]=cadd(u2,m3); v[6]=csub(u2,m3);
    cplx z0=t4;
    cplx z1 = (S>0) ? make_float2(C*(t5.x-t5.y), C*(t5.y+t5.x))
                    : make_float2(C*(t5.x+t5.y), C*(t5.y-t5.x));
    cplx z2 = imul<S>(t6);
    cplx z3 = (S>0) ? make_float2(C*(-t7.x-t7.y), C*( t7.x-t7.y))
                    : make_float2(C*(-t7.x+t7.y), C*(-t7.x-t7.y));
    cplx w0=cadd(z0,z2), w2=csub(z0,z2);
    cplx w1=cadd(z1,z3), w3=csub(z1,z3);
    v[1]=cadd(w0,w1); v[5]=csub(w0,w1);
    cplx mb=imul<S>(w3);
    v[3]=cadd(w2,mb); v[7]=csub(w2,mb);
}

// Cooperative 64-point DFT among 8 same-wave lanes (j = 0..7), inputs in regs
// as v[n1] = z[8*n1 + j]. Stage-1 exchange uses the 64-slot scratch at
// [base..base+64) with XOR-swizzled slots: slot(a,b) = 8a + (b^a).
// With base stride == 8 (mod 32) this makes BOTH the scatter write
// (banks 8((G+j)&3) + (k^j)) and the gather read (banks 8((G+n)&3) + (j^n))
// exactly 2 lanes/bank == conflict-free. On return v[k2] = X[j + 8*k2].
template<int S>
__device__ __forceinline__ void fft64_from_regs(
    cplx v[8], float* __restrict__ re, float* __restrict__ im,
    int base, int j, const cplx wj[7])
{
    dft8<S>(v);                       // A[j][k1]
    #pragma unroll
    for (int k=1;k<8;++k) v[k] = cmul(v[k], wj[k-1]);   // * w64^(j*k1)
    #pragma unroll
    for (int k=0;k<8;++k){ int s=base+8*j+(k^j); re[s]=v[k].x; im[s]=v[k].y; }
    #pragma unroll
    for (int n=0;n<8;++n){ int s=base+8*n+(j^n); v[n]=make_float2(re[s],im[s]); }
    dft8<S>(v);                       // X[j + 8*k2]
}

template<int S>
__device__ __forceinline__ void make_twiddles(int j, cplx wj[7]) {
    float sn, cs;
    sincosf((float)S * 6.283185307179586f * (float)j / 64.0f, &sn, &cs);
    cplx w1 = make_float2(cs, sn);
    wj[0] = w1;
    #pragma unroll
    for (int k=1;k<7;++k) wj[k] = cmul(wj[k-1], w1);
}

// Forward rfft2 of one 64x64 real image per block.
// Output layout: out[img*2112 + w'*64 + h], scaled by `scale`.
__global__ __launch_bounds__(256) void fwd_fft_kernel(
    const float* __restrict__ in, cplx* __restrict__ out, float scale)
{
    __shared__ __align__(16) float SRe[32*CS + 64], SIm[32*CS + 64];
    const int tid = threadIdx.x, G = tid>>3, j = tid&7;
    cplx wj[7]; make_twiddles<-1>(j, wj);

    const float* img = in + (size_t)blockIdx.x * 4096;

    // row pass: pack rows (G, G+32): z[w] = row_G[w] + i*row_{G+32}[w]
    {
        cplx v[8];
        #pragma unroll
        for (int nn=0;nn<8;++nn){ int w=8*nn+j;
            v[nn] = make_float2(img[64*G + w], img[64*(G+32) + w]); }
        int base = CS*G;
        fft64_from_regs<-1>(v, SRe, SIm, base, j, wj);
        #pragma unroll
        for (int k=0;k<8;++k){ int s=base+j+8*k; SRe[s]=v[k].x; SIm[s]=v[k].y; }
    }
    __syncthreads();

    // column pass: group 0 handles packed columns (0,32); group G -> column G.
    {
        cplx v[8];
        if (G == 0) {
            #pragma unroll
            for (int nn=0;nn<8;++nn){
                int r=8*nn+j, p=r&31, hi=r>>5;
                float a0 =SRe[CS*p + 0],  b0 =SIm[CS*p + 0];
                float a32=SRe[CS*p + 32], b32=SIm[CS*p + 32];
                v[nn] = hi ? make_float2(b0, b32) : make_float2(a0, a32);
            }
        } else {
            const int c = G;
            #pragma unroll
            for (int nn=0;nn<8;++nn){
                int r=8*nn+j, p=r&31, hi=r>>5;
                cplx A  = make_float2(SRe[CS*p + c],      SIm[CS*p + c]);
                cplx Bm = make_float2(SRe[CS*p + 64 - c], SIm[CS*p + 64 - c]);
                if (!hi) v[nn] = make_float2(0.5f*(A.x + Bm.x), 0.5f*(A.y - Bm.y));
                else { float dx = A.x - Bm.x, dy = A.y + Bm.y;
                       v[nn] = make_float2(0.5f*dy, -0.5f*dx); }
            }
        }
        __syncthreads();              // row-pass data fully consumed into regs
        int base = CS*G;
        fft64_from_regs<-1>(v, SRe, SIm, base, j, wj);
        #pragma unroll
        for (int k=0;k<8;++k){ int s=base+j+8*k; SRe[s]=v[k].x; SIm[s]=v[k].y; }
    }
    __syncthreads();

    // unpack packed column 0 -> true columns 0 and 32; store all.
    cplx* o = out + (size_t)blockIdx.x * FBINS;
    for (int i = tid; i < FBINS; i += 256) {
        int wp = i>>6, h = i&63;
        cplx r;
        if (wp == 0) {
            int h2 = (64-h)&63;
            cplx a = make_float2(SRe[h],  SIm[h]);
            cplx bb= make_float2(SRe[h2], SIm[h2]);
            r = make_float2(0.5f*(a.x+bb.x), 0.5f*(a.y-bb.y));
        } else if (wp == 32) {
            int h2 = (64-h)&63;
            cplx a = make_float2(SRe[h],  SIm[h]);
            cplx bb= make_float2(SRe[h2], SIm[h2]);
            float dx = a.x-bb.x, dy = a.y+bb.y;
            r = make_float2(0.5f*dy, -0.5f*dx);
        } else {
            r = make_float2(SRe[CS*wp + h], SIm[CS*wp + h]);
        }
        o[i] = make_float2(r.x*scale, r.y*scale);
    }
}

__global__ __launch_bounds__(256) void norm_kernel(
    const float* __restrict__ x, const float* __restrict__ y,
    float* __restrict__ xn, float* __restrict__ yn)
{
    __shared__ float red[4];
    const int blk = blockIdx.x;
    const float* p = (blk < 32) ? x + (size_t)blk * 12288
                                : y + (size_t)(blk - 32) * 12288;
    const float4* p4 = (const float4*)p;
    float s = 0.f;
    for (int i = threadIdx.x; i < 3072; i += 256) {
        float4 v = p4[i];
        s += v.x*v.x + v.y*v.y + v.z*v.z + v.w*v.w;
    }
    #pragma unroll
    for (int off = 32; off; off >>= 1) s += __shfl_xor(s, off);
    if ((threadIdx.x & 63) == 0) red[threadIdx.x >> 6] = s;
    __syncthreads();
    if (threadIdx.x == 0) {
        float t = red[0] + red[1] + red[2] + red[3];
        if (blk < 32) xn[blk] = sqrtf(t); else yn[blk - 32] = sqrtf(t);
    }
}

// One block per (b,n) pair, XCD-tiled: XCD x owns n in [64x, 64x+64).
__global__ __launch_bounds__(256) void corr_kernel(
    const cplx* __restrict__ Xf, const cplx* __restrict__ Yf,
    const float* __restrict__ xn, const float* __restrict__ yn,
    float* __restrict__ out)
{
    __shared__ __align__(16) float SRe[32*CS + 64], SIm[32*CS + 64];
    __shared__ float red[4];
    const int tid = threadIdx.x, G = tid>>3, j = tid&7;

    const int blk = blockIdx.x;
    const int xcd = blk & 7, idx = blk >> 3;
    const int n = xcd*64 + (idx & 63);
    const int b = idx >> 6;

    cplx wj[7]; make_twiddles<1>(j, wj);

    // step A: G[h][w'] = sum_c conj(X)*Y; bin pairs via float4 loads,
    // float2 LDS writes (pairs never straddle a column: bin even).
    const float4* Xb4 = (const float4*)(Xf + (size_t)b * 3 * FBINS);
    const float4* Yn4 = (const float4*)(Yf + (size_t)n * 3 * FBINS);
    #pragma unroll
    for (int t = 0; t < 5; ++t) {
        int i = tid + t*256;              // pair index, 1056 pairs
        if (i < 1056) {
            float a0x=0.f, a0y=0.f, a1x=0.f, a1y=0.f;
            #pragma unroll
            for (int ch = 0; ch < 3; ++ch) {
                float4 a = Xb4[ch*1056 + i];
                float4 c = Yn4[ch*1056 + i];
                a0x += a.x*c.x + a.y*c.y;  a0y += a.x*c.y - a.y*c.x;
                a1x += a.z*c.z + a.w*c.w;  a1y += a.z*c.w - a.w*c.z;
            }
            int bin = 2*i;
            int s = CS*(bin>>6) + (bin&63);
            *(float2*)&SRe[s] = make_float2(a0x, a1x);
            *(float2*)&SIm[s] = make_float2(a0y, a1y);
        }
    }
    __syncthreads();

    // step B: inverse FFT along h per column; group 0 packs cols 0 & 32.
    {
        cplx v[8];
        int base = CS*G;
        if (G == 0) {
            #pragma unroll
            for (int nn=0;nn<8;++nn){
                int h = 8*nn + j;
                cplx a = make_float2(SRe[h],           SIm[h]);
                cplx c = make_float2(SRe[CS*32 + h],   SIm[CS*32 + h]);
                v[nn] = make_float2(a.x - c.y, a.y + c.x);  // a + i*c
            }
        } else {
            #pragma unroll
            for (int nn=0;nn<8;++nn){ int s = base + 8*nn + j;
                v[nn] = make_float2(SRe[s], SIm[s]); }
        }
        fft64_from_regs<1>(v, SRe, SIm, base, j, wj);
        #pragma unroll
        for (int k=0;k<8;++k){ int s = base + j + 8*k; SRe[s]=v[k].x; SIm[s]=v[k].y; }
    }
    __syncthreads();
    // column 0 now holds (c0[h], c32[h]) real pair; cols 1..31 complex.

    // step C: inverse FFT along w, rows packed pairwise (r1=G, r2=G+32).
    float m = -3.4e38f;
    {
        const int r1 = G, r2 = G + 32;
        cplx v[8];
        if (j == 0) {
            v[0] = make_float2(SRe[r1], SRe[r2]);             // w=0: c0 pair
        } else {
            cplx a = make_float2(SRe[CS*j + r1], SIm[CS*j + r1]);
            cplx c = make_float2(SRe[CS*j + r2], SIm[CS*j + r2]);
            v[0] = make_float2(a.x - c.y, a.y + c.x);
        }
        #pragma unroll
        for (int nn=1; nn<4; ++nn) {                          // w = 8..31
            int w = 8*nn + j;
            cplx a = make_float2(SRe[CS*w + r1], SIm[CS*w + r1]);
            cplx c = make_float2(SRe[CS*w + r2], SIm[CS*w + r2]);
            v[nn] = make_float2(a.x - c.y, a.y + c.x);
        }
        if (j == 0) {
            v[4] = make_float2(SIm[r1], SIm[r2]);             // w=32: c32 pair
        } else {
            int w2 = 32 - j;
            cplx a = make_float2(SRe[CS*w2 + r1], SIm[CS*w2 + r1]);
            cplx c = make_float2(SRe[CS*w2 + r2], SIm[CS*w2 + r2]);
            v[4] = make_float2(a.x + c.y, -a.y + c.x);        // conj ext
        }
        #pragma unroll
        for (int nn=5; nn<8; ++nn) {                          // w = 40..63
            int w2 = 64 - (8*nn + j);
            cplx a = make_float2(SRe[CS*w2 + r1], SIm[CS*w2 + r1]);
            cplx c = make_float2(SRe[CS*w2 + r2], SIm[CS*w2 + r2]);
            v[nn] = make_float2(a.x + c.y, -a.y + c.x);
        }
        __syncthreads();              // all rows consumed; S becomes scratch
        fft64_from_regs<1>(v, SRe, SIm, CS*G, j, wj);
        #pragma unroll
        for (int k=0;k<8;++k) m = fmaxf(m, fmaxf(v[k].x, v[k].y));
    }
    #pragma unroll
    for (int off = 32; off; off >>= 1) m = fmaxf(m, __shfl_xor(m, off));
    if ((tid & 63) == 0) red[tid >> 6] = m;
    __syncthreads();
    if (tid == 0) {
        float mm = fmaxf(fmaxf(red[0], red[1]), fmaxf(red[2], red[3]));
        out[b*512 + n] = mm / (xn[b] * yn[n]);
    }
}

extern "C" void kernel_launch(void* const* d_in, const int* in_sizes, int n_in,
                              void* d_out, int out_size, void* d_ws, size_t ws_size,
                              hipStream_t stream) {
    const float* x = (const float*)d_in[0];   // (32,3,64,64)
    const float* y = (const float*)d_in[1];   // (512,3,64,64)
    float* out = (float*)d_out;               // (32,512)

    cplx* Xf = (cplx*)d_ws;
    cplx* Yf = Xf + 96 * FBINS;
    float* xn = (float*)(Yf + 1536 * FBINS);
    float* yn = xn + 32;

    fwd_fft_kernel<<<96,   256, 0, stream>>>(x, Xf, 1.0f / 4096.0f);
    fwd_fft_kernel<<<1536, 256, 0, stream>>>(y, Yf, 1.0f);
    norm_kernel<<<544, 256, 0, stream>>>(x, y, xn, yn);
    corr_kernel<<<16384, 256, 0, stream>>>(Xf, Yf, xn, yn, out);
}

// Round 4
// 110.300 us; speedup vs baseline: 2.8219x; 1.0554x over previous
//
#include <hip/hip_runtime.h>
#include <math.h>

#define FBINS 2112            // 33 * 64 bins, layout: bin = w'*64 + h
#define CS 72                 // LDS column stride in floats; 72 % 32 == 8

typedef float2 cplx;

__device__ __forceinline__ cplx cadd(cplx a, cplx b){ return make_float2(a.x+b.x, a.y+b.y); }
__device__ __forceinline__ cplx csub(cplx a, cplx b){ return make_float2(a.x-b.x, a.y-b.y); }
template<int S> __device__ __forceinline__ cplx imul(cplx a){   // (i*S) * a
    return (S > 0) ? make_float2(-a.y, a.x) : make_float2(a.y, -a.x);
}
// Twiddle table stores inverse-direction W = exp(+2*pi*i*m/64).
// S=+1: a*W ; S=-1: a*conj(W). Same instruction count either way.
template<int S> __device__ __forceinline__ cplx cmul_tw(cplx a, cplx w){
    return (S > 0) ? make_float2(a.x*w.x - a.y*w.y, a.x*w.y + a.y*w.x)
                   : make_float2(a.x*w.x + a.y*w.y, a.y*w.x - a.x*w.y);
}

// Hardcoded 8-point DFT: X[k] = sum_n v[n] * w8^(n*k), w8 = exp(i*S*pi/4).
template<int S>
__device__ __forceinline__ void dft8(cplx v[8]) {
    const float C = 0.70710678118654752440f;
    cplx t0=cadd(v[0],v[4]), t4=csub(v[0],v[4]);
    cplx t1=cadd(v[1],v[5]), t5=csub(v[1],v[5]);
    cplx t2=cadd(v[2],v[6]), t6=csub(v[2],v[6]);
    cplx t3=cadd(v[3],v[7]), t7=csub(v[3],v[7]);
    cplx u0=cadd(t0,t2), u2=csub(t0,t2);
    cplx u1=cadd(t1,t3), u3=csub(t1,t3);
    v[0]=cadd(u0,u1); v[4]=csub(u0,u1);
    cplx m3=imul<S>(u3);
    v[2]=cadd(u2,m3); v[6]=csub(u2,m3);
    cplx z0=t4;
    cplx z1 = (S>0) ? make_float2(C*(t5.x-t5.y), C*(t5.y+t5.x))
                    : make_float2(C*(t5.x+t5.y), C*(t5.y-t5.x));
    cplx z2 = imul<S>(t6);
    cplx z3 = (S>0) ? make_float2(C*(-t7.x-t7.y), C*( t7.x-t7.y))
                    : make_float2(C*(-t7.x+t7.y), C*(-t7.x-t7.y));
    cplx w0=cadd(z0,z2), w2=csub(z0,z2);
    cplx w1=cadd(z1,z3), w3=csub(z1,z3);
    v[1]=cadd(w0,w1); v[5]=csub(w0,w1);
    cplx mb=imul<S>(w3);
    v[3]=cadd(w2,mb); v[7]=csub(w2,mb);
}

// Cooperative 64-point DFT among 8 same-wave lanes (j = 0..7), inputs in regs
// as v[n1] = z[8*n1 + j]. Stage-1 exchange uses 64-slot scratch at
// [base..base+64) with XOR-swizzled slots slot(a,b) = 8a + (b^a); with
// base stride == 8 (mod 32) both scatter write and gather read are exactly
// 2 lanes/bank (free). On return v[k2] = X[j + 8*k2].
template<int S>
__device__ __forceinline__ void fft64_from_regs(
    cplx v[8], float* __restrict__ re, float* __restrict__ im,
    int base, int j, const cplx wj[7])
{
    dft8<S>(v);                       // A[j][k1]
    #pragma unroll
    for (int k=1;k<8;++k) v[k] = cmul_tw<S>(v[k], wj[k-1]);  // * w64^(S*j*k1)
    #pragma unroll
    for (int k=0;k<8;++k){ int s=base+8*j+(k^j); re[s]=v[k].x; im[s]=v[k].y; }
    #pragma unroll
    for (int n=0;n<8;++n){ int s=base+8*n+(j^n); v[n]=make_float2(re[s],im[s]); }
    dft8<S>(v);                       // X[j + 8*k2]
}

// 56-entry twiddle table: TWS[j*7 + k] = exp(+2*pi*i * j*(k+1) / 64),
// j=0..7, k=0..6. Computed once per block by 56 threads (needs a barrier
// between init and first read).
__device__ __forceinline__ void init_twtable(cplx* TWS, int tid){
    if (tid < 56) {
        int jj = tid / 7, kk = tid - 7*jj + 1;
        float sn, cs;
        sincosf(6.283185307179586f * (float)(jj*kk) / 64.0f, &sn, &cs);
        TWS[tid] = make_float2(cs, sn);
    }
}
__device__ __forceinline__ void load_tw(const cplx* TWS, int j, cplx wj[7]){
    #pragma unroll
    for (int k=0;k<7;++k) wj[k] = TWS[j*7+k];
}

// Forward rfft2 of one 64x64 real image per block; also emits sum(img^2)
// partial for the norm. Output: out[img*2112 + w'*64 + h] * scale.
__global__ __launch_bounds__(256) void fwd_fft_kernel(
    const float* __restrict__ in, cplx* __restrict__ out, float scale,
    float* __restrict__ pn)
{
    __shared__ __align__(16) float SRe[32*CS + 64], SIm[32*CS + 64];
    __shared__ cplx TWS[56];
    __shared__ float red[4];
    const int tid = threadIdx.x, G = tid>>3, j = tid&7;

    init_twtable(TWS, tid);

    const float* img = in + (size_t)blockIdx.x * 4096;

    // row pass: pack rows (G, G+32): z[w] = row_G[w] + i*row_{G+32}[w].
    // Accumulate the squared-norm partial while the pixels are in regs.
    cplx wj[7];
    {
        cplx v[8];
        float ns = 0.f;
        #pragma unroll
        for (int nn=0;nn<8;++nn){ int w=8*nn+j;
            float a = img[64*G + w], c = img[64*(G+32) + w];
            v[nn] = make_float2(a, c);
            ns = fmaf(a, a, ns); ns = fmaf(c, c, ns); }
        #pragma unroll
        for (int off = 32; off; off >>= 1) ns += __shfl_xor(ns, off);
        if ((tid & 63) == 0) red[tid >> 6] = ns;
        __syncthreads();              // TWS ready + red ready
        load_tw(TWS, j, wj);
        int base = CS*G;
        fft64_from_regs<-1>(v, SRe, SIm, base, j, wj);
        #pragma unroll
        for (int k=0;k<8;++k){ int s=base+j+8*k; SRe[s]=v[k].x; SIm[s]=v[k].y; }
    }
    __syncthreads();

    // column pass: group 0 handles packed columns (0,32); group G -> column G.
    {
        cplx v[8];
        if (G == 0) {
            #pragma unroll
            for (int nn=0;nn<8;++nn){
                int r=8*nn+j, p=r&31, hi=r>>5;
                float a0 =SRe[CS*p + 0],  b0 =SIm[CS*p + 0];
                float a32=SRe[CS*p + 32], b32=SIm[CS*p + 32];
                v[nn] = hi ? make_float2(b0, b32) : make_float2(a0, a32);
            }
        } else {
            const int c = G;
            #pragma unroll
            for (int nn=0;nn<8;++nn){
                int r=8*nn+j, p=r&31, hi=r>>5;
                cplx A  = make_float2(SRe[CS*p + c],      SIm[CS*p + c]);
                cplx Bm = make_float2(SRe[CS*p + 64 - c], SIm[CS*p + 64 - c]);
                if (!hi) v[nn] = make_float2(0.5f*(A.x + Bm.x), 0.5f*(A.y - Bm.y));
                else { float dx = A.x - Bm.x, dy = A.y + Bm.y;
                       v[nn] = make_float2(0.5f*dy, -0.5f*dx); }
            }
        }
        __syncthreads();              // row-pass data fully consumed into regs
        int base = CS*G;
        fft64_from_regs<-1>(v, SRe, SIm, base, j, wj);
        #pragma unroll
        for (int k=0;k<8;++k){ int s=base+j+8*k; SRe[s]=v[k].x; SIm[s]=v[k].y; }
    }
    __syncthreads();

    // unpack packed column 0 -> true columns 0 and 32; store all.
    cplx* o = out + (size_t)blockIdx.x * FBINS;
    for (int i = tid; i < FBINS; i += 256) {
        int wp = i>>6, h = i&63;
        cplx r;
        if (wp == 0) {
            int h2 = (64-h)&63;
            cplx a = make_float2(SRe[h],  SIm[h]);
            cplx bb= make_float2(SRe[h2], SIm[h2]);
            r = make_float2(0.5f*(a.x+bb.x), 0.5f*(a.y-bb.y));
        } else if (wp == 32) {
            int h2 = (64-h)&63;
            cplx a = make_float2(SRe[h],  SIm[h]);
            cplx bb= make_float2(SRe[h2], SIm[h2]);
            float dx = a.x-bb.x, dy = a.y+bb.y;
            r = make_float2(0.5f*dy, -0.5f*dx);
        } else {
            r = make_float2(SRe[CS*wp + h], SIm[CS*wp + h]);
        }
        o[i] = make_float2(r.x*scale, r.y*scale);
    }
    if (tid == 0) pn[blockIdx.x] = red[0] + red[1] + red[2] + red[3];
}

// One block per (b,n) pair, XCD-tiled: XCD x owns n in [64x, 64x+64).
__global__ __launch_bounds__(256) void corr_kernel(
    const cplx* __restrict__ Xf, const cplx* __restrict__ Yf,
    const float* __restrict__ px, const float* __restrict__ py,
    float* __restrict__ out)
{
    __shared__ __align__(16) float SRe[32*CS + 64], SIm[32*CS + 64];
    __shared__ cplx TWS[56];
    __shared__ float red[4];
    const int tid = threadIdx.x, G = tid>>3, j = tid&7;

    const int blk = blockIdx.x;
    const int xcd = blk & 7, idx = blk >> 3;
    const int n = xcd*64 + (idx & 63);
    const int b = idx >> 6;

    init_twtable(TWS, tid);

    // norm factor (broadcast L2 loads, fully hidden under step A)
    const float x2 = px[3*b] + px[3*b+1] + px[3*b+2];
    const float y2 = py[3*n] + py[3*n+1] + py[3*n+2];
    const float dinv = rsqrtf(x2 * y2);

    // step A: G[h][w'] = sum_c conj(X)*Y; bin pairs via float4 loads,
    // float2 LDS writes (pairs never straddle a column: bin even).
    const float4* Xb4 = (const float4*)(Xf + (size_t)b * 3 * FBINS);
    const float4* Yn4 = (const float4*)(Yf + (size_t)n * 3 * FBINS);
    #pragma unroll
    for (int t = 0; t < 5; ++t) {
        int i = tid + t*256;              // pair index, 1056 pairs
        if (i < 1056) {
            float a0x=0.f, a0y=0.f, a1x=0.f, a1y=0.f;
            #pragma unroll
            for (int ch = 0; ch < 3; ++ch) {
                float4 a = Xb4[ch*1056 + i];
                float4 c = Yn4[ch*1056 + i];
                a0x += a.x*c.x + a.y*c.y;  a0y += a.x*c.y - a.y*c.x;
                a1x += a.z*c.z + a.w*c.w;  a1y += a.z*c.w - a.w*c.z;
            }
            int bin = 2*i;
            int s = CS*(bin>>6) + (bin&63);
            *(float2*)&SRe[s] = make_float2(a0x, a1x);
            *(float2*)&SIm[s] = make_float2(a0y, a1y);
        }
    }
    __syncthreads();                      // step-A data + TWS ready

    cplx wj[7]; load_tw(TWS, j, wj);

    // step B: inverse FFT along h per column; group 0 packs cols 0 & 32.
    {
        cplx v[8];
        int base = CS*G;
        if (G == 0) {
            #pragma unroll
            for (int nn=0;nn<8;++nn){
                int h = 8*nn + j;
                cplx a = make_float2(SRe[h],           SIm[h]);
                cplx c = make_float2(SRe[CS*32 + h],   SIm[CS*32 + h]);
                v[nn] = make_float2(a.x - c.y, a.y + c.x);  // a + i*c
            }
        } else {
            #pragma unroll
            for (int nn=0;nn<8;++nn){ int s = base + 8*nn + j;
                v[nn] = make_float2(SRe[s], SIm[s]); }
        }
        fft64_from_regs<1>(v, SRe, SIm, base, j, wj);
        #pragma unroll
        for (int k=0;k<8;++k){ int s = base + j + 8*k; SRe[s]=v[k].x; SIm[s]=v[k].y; }
    }
    __syncthreads();
    // column 0 now holds (c0[h], c32[h]) real pair; cols 1..31 complex.

    // step C: inverse FFT along w, rows packed pairwise (r1=G, r2=G+32).
    float m = -3.4e38f;
    {
        const int r1 = G, r2 = G + 32;
        cplx v[8];
        if (j == 0) {
            v[0] = make_float2(SRe[r1], SRe[r2]);             // w=0: c0 pair
        } else {
            cplx a = make_float2(SRe[CS*j + r1], SIm[CS*j + r1]);
            cplx c = make_float2(SRe[CS*j + r2], SIm[CS*j + r2]);
            v[0] = make_float2(a.x - c.y, a.y + c.x);
        }
        #pragma unroll
        for (int nn=1; nn<4; ++nn) {                          // w = 8..31
            int w = 8*nn + j;
            cplx a = make_float2(SRe[CS*w + r1], SIm[CS*w + r1]);
            cplx c = make_float2(SRe[CS*w + r2], SIm[CS*w + r2]);
            v[nn] = make_float2(a.x - c.y, a.y + c.x);
        }
        if (j == 0) {
            v[4] = make_float2(SIm[r1], SIm[r2]);             // w=32: c32 pair
        } else {
            int w2 = 32 - j;
            cplx a = make_float2(SRe[CS*w2 + r1], SIm[CS*w2 + r1]);
            cplx c = make_float2(SRe[CS*w2 + r2], SIm[CS*w2 + r2]);
            v[4] = make_float2(a.x + c.y, -a.y + c.x);        // conj ext
        }
        #pragma unroll
        for (int nn=5; nn<8; ++nn) {                          // w = 40..63
            int w2 = 64 - (8*nn + j);
            cplx a = make_float2(SRe[CS*w2 + r1], SIm[CS*w2 + r1]);
            cplx c = make_float2(SRe[CS*w2 + r2], SIm[CS*w2 + r2]);
            v[nn] = make_float2(a.x + c.y, -a.y + c.x);
        }
        __syncthreads();              // all rows consumed; S becomes scratch
        fft64_from_regs<1>(v, SRe, SIm, CS*G, j, wj);
        #pragma unroll
        for (int k=0;k<8;++k) m = fmaxf(m, fmaxf(v[k].x, v[k].y));
    }
    #pragma unroll
    for (int off = 32; off; off >>= 1) m = fmaxf(m, __shfl_xor(m, off));
    if ((tid & 63) == 0) red[tid >> 6] = m;
    __syncthreads();
    if (tid == 0) {
        float mm = fmaxf(fmaxf(red[0], red[1]), fmaxf(red[2], red[3]));
        out[b*512 + n] = mm * dinv;
    }
}

extern "C" void kernel_launch(void* const* d_in, const int* in_sizes, int n_in,
                              void* d_out, int out_size, void* d_ws, size_t ws_size,
                              hipStream_t stream) {
    const float* x = (const float*)d_in[0];   // (32,3,64,64)
    const float* y = (const float*)d_in[1];   // (512,3,64,64)
    float* out = (float*)d_out;               // (32,512)

    cplx* Xf = (cplx*)d_ws;
    cplx* Yf = Xf + 96 * FBINS;
    float* px = (float*)(Yf + 1536 * FBINS);  // 96 per-(image,channel) sumsq
    float* py = px + 96;                      // 1536 per-(image,channel) sumsq

    fwd_fft_kernel<<<96,   256, 0, stream>>>(x, Xf, 1.0f / 4096.0f, px);
    fwd_fft_kernel<<<1536, 256, 0, stream>>>(y, Yf, 1.0f, py);
    corr_kernel<<<16384, 256, 0, stream>>>(Xf, Yf, px, py, out);
}